// Round 2
// baseline (1372.993 us; speedup 1.0000x reference)
//
#include <hip/hip_runtime.h>
#include <hip/hip_bf16.h>

#define N0 200000
#define N1 150000
#define N2 120000
#define N3 100000
#define E0 2000000
#define E1 1000000
#define E2 500000
#define ESUB 250000

// cnt/offs super-array layout: [c2 | c0s | c0d | c1]
// c2 FIRST so the g2 pool segment is exactly pool[0..E2) -> x3b can alias pool+E2.
#define IC2 0
#define IC0S N3
#define IC0D (N3 + N1)
#define IC1 (N3 + 2 * N1)
#define LTOT (N3 + 2 * N1 + N2)      // 520000
#define NBLK ((LTOT + 2047) / 2048)  // 254 (fits one 256-thread scan block)
#define POOLCAP (E2 + 2 * E0 + E1)   // 5,500,000 slots (upper bound)

// coarse buckets: 512 nodes per bucket (node >> 9)
#define NC2  ((N3 + 511) / 512)      // 196
#define NC0  ((N1 + 511) / 512)      // 293
#define NC1  ((N2 + 511) / 512)      // 235
#define CC2  0
#define CC0S NC2
#define CC0D (NC2 + NC0)
#define CC1  (NC2 + 2 * NC0)
#define CCTOT 1024                   // >= 196+293+293+235 = 1017

#define BINCHUNK 4096

typedef float f32x4 __attribute__((ext_vector_type(4)));
typedef __bf16 bf16x8 __attribute__((ext_vector_type(8)));

// ---------------- counting ----------------
__global__ void k_cnt0(const int* __restrict__ src, const int* __restrict__ dst,
                       int* __restrict__ cnt) {
    int i = blockIdx.x * blockDim.x + threadIdx.x;
    if (i >= E0) return;
    int s = src[i];
    if (s < N1) atomicAdd(&cnt[IC0S + s], 1);
    atomicAdd(&cnt[IC0D + dst[i]], 1);
}

__global__ void k_cnt2(const int* __restrict__ src, const int* __restrict__ dst, int n,
                       int* __restrict__ dego, int* __restrict__ cnt, int cbase) {
    int i = blockIdx.x * blockDim.x + threadIdx.x;
    if (i >= n) return;
    atomicAdd(&dego[src[i]], 1);
    atomicAdd(&cnt[cbase + dst[i]], 1);
}

// ---------------- exclusive scan (3-kernel hierarchical, exact) ----------------
__global__ __launch_bounds__(256) void k_scan1(const int* __restrict__ cnt,
                                               int* __restrict__ offs, int* __restrict__ bsum) {
    __shared__ int ts[256];
    int t = threadIdx.x;
    int base = blockIdx.x * 2048 + t * 8;
    int loc[8];
    int s = 0;
#pragma unroll
    for (int j = 0; j < 8; j++) {
        int v = (base + j < LTOT) ? cnt[base + j] : 0;
        loc[j] = s; s += v;
    }
    ts[t] = s;
    __syncthreads();
    for (int off = 1; off < 256; off <<= 1) {
        int x = (t >= off) ? ts[t - off] : 0;
        __syncthreads();
        ts[t] += x;
        __syncthreads();
    }
    int excl = ts[t] - s;
#pragma unroll
    for (int j = 0; j < 8; j++)
        if (base + j < LTOT) offs[base + j] = excl + loc[j];
    if (t == 255) bsum[blockIdx.x] = ts[255];
}

__global__ __launch_bounds__(256) void k_scan2(const int* __restrict__ bsum,
                                               int* __restrict__ bscan) {
    __shared__ int ts[256];
    int t = threadIdx.x;
    int v = (t < NBLK) ? bsum[t] : 0;
    ts[t] = v;
    __syncthreads();
    for (int off = 1; off < 256; off <<= 1) {
        int x = (t >= off) ? ts[t - off] : 0;
        __syncthreads();
        ts[t] += x;
        __syncthreads();
    }
    if (t < NBLK) bscan[t] = ts[t] - v;
}

__global__ void k_scan3(int* __restrict__ offs, const int* __restrict__ bscan,
                        const int* __restrict__ bsum) {
    int i = blockIdx.x * 256 + threadIdx.x;
    if (i < LTOT) offs[i] += bscan[i >> 11];
    if (i == 0) offs[LTOT] = bscan[NBLK - 1] + bsum[NBLK - 1];
}

// ---------------- two-level binning ----------------
// Pass A: chunked LDS histogram over coarse buckets (node>>9), one global atomic
// per (block,bucket) reserves a dense run in the coarse pool. Entry packs
// (node & 511) << 18 | payload  (payload < 2^18: typ<500, src<200000).
__global__ __launch_bounds__(256) void k_binA(const int* __restrict__ dst, const int* __restrict__ aux,
                                              int n, int limit,
                                              const int* __restrict__ offs, int cbase,
                                              int* __restrict__ ccur, int ccbase,
                                              int* __restrict__ cpool) {
    __shared__ int lcnt[512], lbase[512], lcur[512];
    int t = threadIdx.x;
    lcnt[t] = 0; lcnt[t + 256] = 0;
    lcur[t] = 0; lcur[t + 256] = 0;
    __syncthreads();
    int e0 = blockIdx.x * BINCHUNK;
    int e1 = n - e0; if (e1 > BINCHUNK) e1 = BINCHUNK; e1 += e0;
    for (int i = e0 + t; i < e1; i += 256) {
        int d = dst[i];
        if (d < limit) atomicAdd(&lcnt[d >> 9], 1);
    }
    __syncthreads();
    for (int b = t; b < 512; b += 256) {
        int c = lcnt[b];
        if (c > 0) lbase[b] = offs[cbase + (b << 9)] + atomicAdd(&ccur[ccbase + b], c);
    }
    __syncthreads();
    for (int i = e0 + t; i < e1; i += 256) {
        int d = dst[i];
        if (d < limit) {
            int b = d >> 9;
            int r = atomicAdd(&lcur[b], 1);
            cpool[lbase[b] + r] = ((d & 511) << 18) | aux[i];
        }
    }
}

// Pass B: one block per coarse bucket; reads its contiguous coarse region and
// scatters into exact CSR slots (target window ~14KB -> L2-dense writeback).
__global__ __launch_bounds__(256) void k_binB(const int* __restrict__ offs, int cbase, int n_nodes,
                                              const int* __restrict__ cpool, int* __restrict__ pool) {
    __shared__ int lofs[512], lcur[512];
    int t = threadIdx.x;
    int n0 = blockIdx.x << 9;
    int nodes = n_nodes - n0; if (nodes > 512) nodes = 512;
    for (int j = t; j < nodes; j += 256) { lofs[j] = offs[cbase + n0 + j]; lcur[j] = 0; }
    __syncthreads();
    int R0 = offs[cbase + n0];
    int Rend = offs[cbase + n0 + nodes];
    for (int i = R0 + t; i < Rend; i += 256) {
        int p = cpool[i];
        int low = p >> 18;
        int r = atomicAdd(&lcur[low], 1);
        pool[lofs[low] + r] = p & 0x3FFFF;
    }
}

// ---------------- layer 0: gather rel_emb means (LDS-cached table) + 32x32 matvecs -> h1 ----------------
__global__ __launch_bounds__(256) void k_layer0(const int* __restrict__ cnt, const int* __restrict__ offs,
                                                const int* __restrict__ pool, const float* __restrict__ rel_emb,
                                                const float* __restrict__ W_out, const float* __restrict__ b_out,
                                                const float* __restrict__ W_in, const float* __restrict__ b_in,
                                                const int* __restrict__ deg1o, float* __restrict__ h1) {
    __shared__ float RE[16000];     // 500 x 32 rel_emb table, 64 KB
    __shared__ float S[4][64];
    int t = threadIdx.x;
    for (int i = t; i < 16000; i += 256) RE[i] = rel_emb[i];
    int nl = t >> 6;
    int lane = t & 63;
    int half = lane >> 5;   // 0 = out(src-agg), 1 = in(dst-agg)
    int k = lane & 31;
    __syncthreads();
    for (int sub = 0; sub < 8; sub++) {
        int n = blockIdx.x * 32 + sub * 4 + nl;
        float acc = 0.0f;
        int dg = 0;
        if (n < N1) {
            int ci = (half ? IC0D : IC0S) + n;
            dg = cnt[ci];
            int off = offs[ci];
            for (int cb = 0; cb < dg; cb += 32) {
                int rem = dg - cb; if (rem > 32) rem = 32;
                int ty_all = (k < rem) ? pool[off + cb + k] : 0;
                for (int i2 = 0; i2 < rem; i2++) {
                    int ty = __shfl(ty_all, i2, 32);     // broadcast within the 32-lane half
                    acc += RE[ty * 32 + k];
                }
            }
        }
        S[nl][lane] = (dg > 0) ? acc / (float)dg : 0.0f;
        __syncthreads();
        if (n < N1) {
            const float* W = half ? W_in : W_out;
            float b = half ? b_in[k] : b_out[k];
            float r = 0.0f;
            if (dg > 0) {
                float dsum = 0.0f;
#pragma unroll
                for (int kk = 0; kk < 32; kk++) dsum += S[nl][half * 32 + kk] * W[kk * 32 + k];
                r = dsum + b;
            }
            h1[(size_t)n * 64 + lane] = r * rsqrtf(fmaxf((float)deg1o[n], 1.0f));
        }
        __syncthreads();
    }
}

// ---------------- conv1 with fused gather ----------------
__global__ __launch_bounds__(256) void k_conv1g(const float* __restrict__ h1,
                                                const int* __restrict__ cnt, const int* __restrict__ offs,
                                                const int* __restrict__ pool, const int* __restrict__ deg2o,
                                                const float* __restrict__ W1, const float* __restrict__ b1,
                                                float* __restrict__ h2) {
    __shared__ float row[8][64];
    int base = blockIdx.x * 8;
    int t = threadIdx.x;
    int wave = t >> 6, lane = t & 63;
#pragma unroll
    for (int rr = 0; rr < 2; rr++) {
        int m = wave * 2 + rr;
        int rg = base + m;                       // grid exact: rg < N2
        int dg = cnt[IC1 + rg];
        int off = offs[IC1 + rg];
        float acc = 0.0f;
        for (int cb = 0; cb < dg; cb += 64) {
            int rem = dg - cb; if (rem > 64) rem = 64;
            int s_all = (lane < rem) ? pool[off + cb + lane] : 0;
            for (int i = 0; i < rem; i++) {
                int s = __shfl(s_all, i, 64);
                acc += h1[(size_t)s * 64 + lane];
            }
        }
        row[m][lane] = acc * rsqrtf(fmaxf((float)dg, 1.0f));
    }
    __syncthreads();
    float acc8[8] = {0, 0, 0, 0, 0, 0, 0, 0};
    for (int k = 0; k < 64; k++) {
        float w = W1[k * 256 + t];
#pragma unroll
        for (int m = 0; m < 8; m++) acc8[m] += row[m][k] * w;
    }
    float bb = b1[t];
#pragma unroll
    for (int m = 0; m < 8; m++) {
        float v = fmaxf(acc8[m] + bb, 0.0f) * rsqrtf(fmaxf((float)deg2o[base + m], 1.0f));
        h2[(size_t)(base + m) * 256 + t] = v;
    }
}

// ---------------- pack W (K x 256 f32, row-major) into MFMA B-fragment order (bf16) ----------------
__global__ void k_pack(const float* __restrict__ W, __bf16* __restrict__ Wp, int ksteps) {
    int idx = blockIdx.x * 256 + threadIdx.x;
    int j = idx & 7;
    int lane = (idx >> 3) & 63;
    int rest = idx >> 9;
    int ks = rest % ksteps;
    int tn = rest / ksteps;
    int k = ks * 32 + ((lane >> 4) * 8) + j;
    int n = tn * 16 + (lane & 15);
    Wp[idx] = (__bf16)W[k * 256 + n];
}

// ---------------- conv2 MFMA with fused gather ----------------
__global__ __launch_bounds__(256) void k_conv2g(const float* __restrict__ h2,
                                                const int* __restrict__ cnt, const int* __restrict__ offs,
                                                const int* __restrict__ pool,
                                                const __bf16* __restrict__ W2p,
                                                const float* __restrict__ b2v,
                                                __bf16* __restrict__ x3b) {
    __shared__ __bf16 At[64][264];   // +8 pad -> 2-way LDS conflicts only
    int t = threadIdx.x;
    int base = blockIdx.x * 64;
    int wave = t >> 6, lane = t & 63;
#pragma unroll 1
    for (int rr = 0; rr < 16; rr++) {
        int row = wave * 16 + rr;
        int rg = base + row;
        f32x4 acc = {0.0f, 0.0f, 0.0f, 0.0f};
        int dg = 0;
        if (rg < N3) {
            dg = cnt[IC2 + rg];
            int off = offs[IC2 + rg];
            for (int cb = 0; cb < dg; cb += 64) {
                int rem = dg - cb; if (rem > 64) rem = 64;
                int s_all = (lane < rem) ? pool[off + cb + lane] : 0;
                for (int i = 0; i < rem; i++) {
                    int s = __shfl(s_all, i, 64);
                    const f32x4 v = *(const f32x4*)(h2 + (size_t)s * 256 + lane * 4);
                    acc += v;
                }
            }
        }
        float sc = rsqrtf(fmaxf((float)dg, 1.0f));
        union { __bf16 b[4]; uint2 u; } cv;
        cv.b[0] = (__bf16)(acc[0] * sc); cv.b[1] = (__bf16)(acc[1] * sc);
        cv.b[2] = (__bf16)(acc[2] * sc); cv.b[3] = (__bf16)(acc[3] * sc);
        *(uint2*)&At[row][lane * 4] = cv.u;
    }
    __syncthreads();
    int q = lane >> 4, r16 = lane & 15;
    f32x4 acc[4][4] = {};
    for (int ks = 0; ks < 8; ks++) {
        bf16x8 a[4], b[4];
        int ko = ks * 32 + q * 8;
#pragma unroll
        for (int mt = 0; mt < 4; mt++)
            a[mt] = *(const bf16x8*)&At[mt * 16 + r16][ko];
#pragma unroll
        for (int i = 0; i < 4; i++) {
            int tn = wave * 4 + i;
            b[i] = *(const bf16x8*)&W2p[((size_t)(tn * 8 + ks) * 64 + lane) * 8];
        }
#pragma unroll
        for (int mt = 0; mt < 4; mt++)
#pragma unroll
            for (int i = 0; i < 4; i++)
                acc[mt][i] = __builtin_amdgcn_mfma_f32_16x16x32_bf16(a[mt], b[i], acc[mt][i], 0, 0, 0);
    }
#pragma unroll
    for (int mt = 0; mt < 4; mt++) {
#pragma unroll
        for (int i = 0; i < 4; i++) {
            int col = (wave * 4 + i) * 16 + r16;
            float bb = b2v[col];
#pragma unroll
            for (int rr = 0; rr < 4; rr++) {
                int row = base + mt * 16 + q * 4 + rr;
                if (row < N3)
                    x3b[(size_t)row * 256 + col] = (__bf16)fmaxf(acc[mt][i][rr] + bb, 0.0f);
            }
        }
    }
}

// ---------------- final via MFMA: out = [x3b[ss], x3b[sd]] @ Wfc + bfc ----------------
__global__ __launch_bounds__(256) void k_final_mfma(const int* __restrict__ ss, const int* __restrict__ sd,
                                                    const __bf16* __restrict__ x3b,
                                                    const __bf16* __restrict__ Wp,
                                                    const float* __restrict__ bfc,
                                                    float* __restrict__ out) {
    __shared__ __bf16 At[64][520];   // +8 pad -> 2-way LDS conflicts only
    __shared__ int eidx[128];
    int t = threadIdx.x;
    int base = blockIdx.x * 64;
    if (t < 64)       { int e = base + t;      eidx[t] = ss[e < ESUB ? e : ESUB - 1]; }
    else if (t < 128) { int e = base + t - 64; eidx[t] = sd[e < ESUB ? e : ESUB - 1]; }
    __syncthreads();
#pragma unroll
    for (int it = 0; it < 16; it++) {
        int c = it * 256 + t;       // 0..4095
        int row = c >> 6;           // 0..63
        int cpos = c & 63;          // 16B chunk within 512-elem row
        int half = cpos >> 5;
        int off8 = (cpos & 31) * 8;
        int node = eidx[half * 64 + row];
        uint4 v = *(const uint4*)(x3b + (size_t)node * 256 + off8);
        *(uint4*)&At[row][half * 256 + off8] = v;
    }
    __syncthreads();
    int wave = t >> 6, lane = t & 63;
    int q = lane >> 4, r16 = lane & 15;
    f32x4 acc[4][4] = {};
    for (int ks = 0; ks < 16; ks++) {
        bf16x8 a[4], b[4];
        int ko = ks * 32 + q * 8;
#pragma unroll
        for (int mt = 0; mt < 4; mt++)
            a[mt] = *(const bf16x8*)&At[mt * 16 + r16][ko];
#pragma unroll
        for (int i = 0; i < 4; i++) {
            int tn = wave * 4 + i;
            b[i] = *(const bf16x8*)&Wp[((size_t)(tn * 16 + ks) * 64 + lane) * 8];
        }
#pragma unroll
        for (int mt = 0; mt < 4; mt++)
#pragma unroll
            for (int i = 0; i < 4; i++)
                acc[mt][i] = __builtin_amdgcn_mfma_f32_16x16x32_bf16(a[mt], b[i], acc[mt][i], 0, 0, 0);
    }
#pragma unroll
    for (int mt = 0; mt < 4; mt++) {
#pragma unroll
        for (int i = 0; i < 4; i++) {
            int col = (wave * 4 + i) * 16 + r16;
            float bb = bfc[col];
#pragma unroll
            for (int rr = 0; rr < 4; rr++) {
                int row = base + mt * 16 + q * 4 + rr;
                if (row < ESUB)
                    out[(size_t)row * 256 + col] = acc[mt][i][rr] + bb;
            }
        }
    }
}

extern "C" void kernel_launch(void* const* d_in, const int* in_sizes, int n_in,
                              void* d_out, int out_size, void* d_ws, size_t ws_size,
                              hipStream_t stream) {
    const int* e0_type = (const int*)d_in[0];
    const int* e0_src  = (const int*)d_in[1];
    const int* e0_dst  = (const int*)d_in[2];
    const int* e1_src  = (const int*)d_in[3];
    const int* e1_dst  = (const int*)d_in[4];
    const int* e2_src  = (const int*)d_in[5];
    const int* e2_dst  = (const int*)d_in[6];
    const int* sub_src = (const int*)d_in[7];
    const int* sub_dst = (const int*)d_in[8];
    const float* rel_emb = (const float*)d_in[9];
    const float* W_out   = (const float*)d_in[10];
    const float* b_out   = (const float*)d_in[11];
    const float* W_in    = (const float*)d_in[12];
    const float* b_in    = (const float*)d_in[13];
    const float* W1      = (const float*)d_in[14];
    const float* b1      = (const float*)d_in[15];
    const float* W2      = (const float*)d_in[16];
    const float* b2v     = (const float*)d_in[17];
    const float* Wfc     = (const float*)d_in[18];
    const float* bfc     = (const float*)d_in[19];
    float* out = (float*)d_out;

    // ---- workspace layout (4-byte units), total ~211 MB ----
    // [cnt | ccur | deg1o | deg2o | offs(+1) | bsum | bscan | pool | cpool | h1 | h2 | Wfcp | W2p]
    int* cnt   = (int*)d_ws;
    int* ccur  = cnt + LTOT;             // 1024 coarse-bucket cursors
    int* deg1o = ccur + CCTOT;           // e1_src out-degree over N1
    int* deg2o = deg1o + N1;             // e2_src out-degree over N2
    int* offs  = deg2o + N2;             // LTOT+1 (last = grand total)
    int* bsum  = offs + LTOT + 1;
    int* bscan = bsum + 512;
    int* pool  = bscan + 512;            // POOLCAP slots; g2 = pool[0..E2)
    int* cpool = pool + POOLCAP;         // coarse (pass-A) pool, same capacity
    float* h1  = (float*)(cpool + POOLCAP);          // N1*64
    float* h2  = h1 + (size_t)N1 * 64;               // N2*256
    __bf16* Wfcp = (__bf16*)(h2 + (size_t)N2 * 256); // 512*256 bf16
    __bf16* W2p  = Wfcp + 131072;                    // 256*256 bf16
    // x3b aliases pool-after-g2 + cpool + head of h1 (all dead by conv2g)
    __bf16* x3b  = (__bf16*)(pool + E2);

    const int BT = 256;

    // zero cnt + ccur + deg1o + deg2o (contiguous, ~3.2 MB)
    hipMemsetAsync(d_ws, 0, (size_t)(LTOT + CCTOT + N1 + N2) * sizeof(int), stream);

    // pack weights (independent of zeroed region)
    k_pack<<<512, BT, 0, stream>>>(Wfc, Wfcp, 16);
    k_pack<<<256, BT, 0, stream>>>(W2, W2p, 8);

    // count
    k_cnt0<<<(E0 + BT - 1) / BT, BT, 0, stream>>>(e0_src, e0_dst, cnt);
    k_cnt2<<<(E1 + BT - 1) / BT, BT, 0, stream>>>(e1_src, e1_dst, E1, deg1o, cnt, IC1);
    k_cnt2<<<(E2 + BT - 1) / BT, BT, 0, stream>>>(e2_src, e2_dst, E2, deg2o, cnt, IC2);

    // exclusive scan of cnt -> offs (+ grand total at offs[LTOT])
    k_scan1<<<NBLK, BT, 0, stream>>>(cnt, offs, bsum);
    k_scan2<<<1, BT, 0, stream>>>(bsum, bscan);
    k_scan3<<<(LTOT + BT - 1) / BT, BT, 0, stream>>>(offs, bscan, bsum);

    // pass A: dense coarse binning
    int nbA0 = (E0 + BINCHUNK - 1) / BINCHUNK;
    int nbA1 = (E1 + BINCHUNK - 1) / BINCHUNK;
    int nbA2 = (E2 + BINCHUNK - 1) / BINCHUNK;
    k_binA<<<nbA2, BT, 0, stream>>>(e2_dst, e2_src, E2, 0x7fffffff, offs, IC2,  ccur, CC2,  cpool);
    k_binA<<<nbA0, BT, 0, stream>>>(e0_src, e0_type, E0, N1,        offs, IC0S, ccur, CC0S, cpool);
    k_binA<<<nbA0, BT, 0, stream>>>(e0_dst, e0_type, E0, 0x7fffffff, offs, IC0D, ccur, CC0D, cpool);
    k_binA<<<nbA1, BT, 0, stream>>>(e1_dst, e1_src, E1, 0x7fffffff, offs, IC1,  ccur, CC1,  cpool);

    // pass B: L2-local scatter into exact CSR slots
    k_binB<<<NC2, BT, 0, stream>>>(offs, IC2,  N3, cpool, pool);
    k_binB<<<NC0, BT, 0, stream>>>(offs, IC0S, N1, cpool, pool);
    k_binB<<<NC0, BT, 0, stream>>>(offs, IC0D, N1, cpool, pool);
    k_binB<<<NC1, BT, 0, stream>>>(offs, IC1,  N2, cpool, pool);

    // layer 0: gather + combine -> h1
    k_layer0<<<(N1 + 31) / 32, BT, 0, stream>>>(cnt, offs, pool, rel_emb, W_out, b_out, W_in, b_in, deg1o, h1);

    // conv1 (fused gather) -> h2
    k_conv1g<<<N2 / 8, BT, 0, stream>>>(h1, cnt, offs, pool, deg2o, W1, b1, h2);

    // conv2 (fused gather, MFMA) -> x3b
    k_conv2g<<<(N3 + 63) / 64, BT, 0, stream>>>(h2, cnt, offs, pool, W2p, b2v, x3b);

    // final edge MLP (MFMA)
    k_final_mfma<<<(ESUB + 63) / 64, BT, 0, stream>>>(sub_src, sub_dst, x3b, Wfcp, bfc, out);
}

// Round 3
// 1167.956 us; speedup vs baseline: 1.1756x; 1.1756x over previous
//
#include <hip/hip_runtime.h>
#include <hip/hip_bf16.h>

#define N0 200000
#define N1 150000
#define N2 120000
#define N3 100000
#define E0 2000000
#define E1 1000000
#define E2 500000
#define ESUB 250000

// cnt/offs super-array layout: [c2 | c0s | c0d | c1]
// c2 FIRST so the g2 pool segment is exactly pool[0..E2) -> x3b can alias pool+E2.
#define IC2 0
#define IC0S N3
#define IC0D (N3 + N1)
#define IC1 (N3 + 2 * N1)
#define LTOT (N3 + 2 * N1 + N2)      // 520000
#define NBLK ((LTOT + 2047) / 2048)  // 254 (fits one 256-thread scan block)
#define POOLCAP (E2 + 2 * E0 + E1)   // 5,500,000 slots (upper bound)

// coarse buckets: 512 nodes per bucket (node >> 9)
#define NC2  ((N3 + 511) / 512)      // 196
#define NC0  ((N1 + 511) / 512)      // 293
#define NC1  ((N2 + 511) / 512)      // 235
#define CC2  0
#define CC0S NC2
#define CC0D (NC2 + NC0)
#define CC1  (NC2 + 2 * NC0)
#define CCTOT 1024                   // >= 196+293+293+235 = 1017

#define BINCHUNK 4096

typedef float f32x4 __attribute__((ext_vector_type(4)));
typedef __bf16 bf16x8 __attribute__((ext_vector_type(8)));

// ---------------- counting ----------------
__global__ void k_cnt0(const int* __restrict__ src, const int* __restrict__ dst,
                       int* __restrict__ cnt) {
    int i = blockIdx.x * blockDim.x + threadIdx.x;
    if (i >= E0) return;
    int s = src[i];
    if (s < N1) atomicAdd(&cnt[IC0S + s], 1);
    atomicAdd(&cnt[IC0D + dst[i]], 1);
}

__global__ void k_cnt2(const int* __restrict__ src, const int* __restrict__ dst, int n,
                       int* __restrict__ dego, int* __restrict__ cnt, int cbase) {
    int i = blockIdx.x * blockDim.x + threadIdx.x;
    if (i >= n) return;
    atomicAdd(&dego[src[i]], 1);
    atomicAdd(&cnt[cbase + dst[i]], 1);
}

// ---------------- exclusive scan (3-kernel hierarchical, exact) ----------------
__global__ __launch_bounds__(256) void k_scan1(const int* __restrict__ cnt,
                                               int* __restrict__ offs, int* __restrict__ bsum) {
    __shared__ int ts[256];
    int t = threadIdx.x;
    int base = blockIdx.x * 2048 + t * 8;
    int loc[8];
    int s = 0;
#pragma unroll
    for (int j = 0; j < 8; j++) {
        int v = (base + j < LTOT) ? cnt[base + j] : 0;
        loc[j] = s; s += v;
    }
    ts[t] = s;
    __syncthreads();
    for (int off = 1; off < 256; off <<= 1) {
        int x = (t >= off) ? ts[t - off] : 0;
        __syncthreads();
        ts[t] += x;
        __syncthreads();
    }
    int excl = ts[t] - s;
#pragma unroll
    for (int j = 0; j < 8; j++)
        if (base + j < LTOT) offs[base + j] = excl + loc[j];
    if (t == 255) bsum[blockIdx.x] = ts[255];
}

__global__ __launch_bounds__(256) void k_scan2(const int* __restrict__ bsum,
                                               int* __restrict__ bscan) {
    __shared__ int ts[256];
    int t = threadIdx.x;
    int v = (t < NBLK) ? bsum[t] : 0;
    ts[t] = v;
    __syncthreads();
    for (int off = 1; off < 256; off <<= 1) {
        int x = (t >= off) ? ts[t - off] : 0;
        __syncthreads();
        ts[t] += x;
        __syncthreads();
    }
    if (t < NBLK) bscan[t] = ts[t] - v;
}

__global__ void k_scan3(int* __restrict__ offs, const int* __restrict__ bscan,
                        const int* __restrict__ bsum) {
    int i = blockIdx.x * 256 + threadIdx.x;
    if (i < LTOT) offs[i] += bscan[i >> 11];
    if (i == 0) offs[LTOT] = bscan[NBLK - 1] + bsum[NBLK - 1];
}

// ---------------- two-level binning ----------------
// Pass A (e1/e2): chunked LDS histogram over coarse buckets (node>>9), one global
// atomic per (block,bucket) reserves a dense run in the coarse pool. Entry packs
// (node & 511) << 18 | payload  (payload < 2^18).
__global__ __launch_bounds__(256) void k_binA(const int* __restrict__ dst, const int* __restrict__ aux,
                                              int n,
                                              const int* __restrict__ offs, int cbase,
                                              int* __restrict__ ccur, int ccbase,
                                              int* __restrict__ cpool) {
    __shared__ int lcnt[512], lbase[512], lcur[512];
    int t = threadIdx.x;
    lcnt[t] = 0; lcnt[t + 256] = 0;
    lcur[t] = 0; lcur[t + 256] = 0;
    __syncthreads();
    int e0 = blockIdx.x * BINCHUNK;
    int e1 = n - e0; if (e1 > BINCHUNK) e1 = BINCHUNK; e1 += e0;
    for (int i = e0 + t; i < e1; i += 256) {
        int d = dst[i];
        atomicAdd(&lcnt[d >> 9], 1);
    }
    __syncthreads();
    for (int b = t; b < 512; b += 256) {
        int c = lcnt[b];
        if (c > 0) lbase[b] = offs[cbase + (b << 9)] + atomicAdd(&ccur[ccbase + b], c);
    }
    __syncthreads();
    for (int i = e0 + t; i < e1; i += 256) {
        int d = dst[i];
        int b = d >> 9;
        int r = atomicAdd(&lcur[b], 1);
        cpool[lbase[b] + r] = ((d & 511) << 18) | aux[i];
    }
}

// Pass A for e0: both sides (src<N1 filtered, dst) in ONE read of the edge arrays.
// lcnt index: side*512 + (node>>9).
__global__ __launch_bounds__(256) void k_binA0(const int* __restrict__ typ,
                                               const int* __restrict__ src, const int* __restrict__ dst,
                                               const int* __restrict__ offs,
                                               int* __restrict__ ccur, int* __restrict__ cpool) {
    __shared__ int lcnt[1024], lbase[1024], lcur[1024];
    int t = threadIdx.x;
#pragma unroll
    for (int j = 0; j < 4; j++) { lcnt[t + j * 256] = 0; lcur[t + j * 256] = 0; }
    __syncthreads();
    int e0 = blockIdx.x * BINCHUNK;
    int e1 = E0 - e0; if (e1 > BINCHUNK) e1 = BINCHUNK; e1 += e0;
    for (int i = e0 + t; i < e1; i += 256) {
        int s = src[i];
        if (s < N1) atomicAdd(&lcnt[s >> 9], 1);
        atomicAdd(&lcnt[512 + (dst[i] >> 9)], 1);
    }
    __syncthreads();
    for (int b = t; b < 1024; b += 256) {
        int c = lcnt[b];
        if (c > 0) {
            int sb = b & 511;
            int lb;
            if (b < 512) lb = offs[IC0S + (sb << 9)] + atomicAdd(&ccur[CC0S + sb], c);
            else         lb = offs[IC0D + (sb << 9)] + atomicAdd(&ccur[CC0D + sb], c);
            lbase[b] = lb;
        }
    }
    __syncthreads();
    for (int i = e0 + t; i < e1; i += 256) {
        int ty = typ[i];
        int s = src[i];
        if (s < N1) {
            int b = s >> 9;
            int r = atomicAdd(&lcur[b], 1);
            cpool[lbase[b] + r] = ((s & 511) << 18) | ty;
        }
        int d = dst[i];
        int b2 = 512 + (d >> 9);
        int r2 = atomicAdd(&lcur[b2], 1);
        cpool[lbase[b2] + r2] = ((d & 511) << 18) | ty;
    }
}

// Pass B: one block per coarse bucket; reads its contiguous coarse region and
// scatters into exact CSR slots (target window ~14KB -> L2-dense writeback).
__global__ __launch_bounds__(256) void k_binB(const int* __restrict__ offs, int cbase, int n_nodes,
                                              const int* __restrict__ cpool, int* __restrict__ pool) {
    __shared__ int lofs[512], lcur[512];
    int t = threadIdx.x;
    int n0 = blockIdx.x << 9;
    int nodes = n_nodes - n0; if (nodes > 512) nodes = 512;
    for (int j = t; j < nodes; j += 256) { lofs[j] = offs[cbase + n0 + j]; lcur[j] = 0; }
    __syncthreads();
    int R0 = offs[cbase + n0];
    int Rend = offs[cbase + n0 + nodes];
    for (int i = R0 + t; i < Rend; i += 256) {
        int p = cpool[i];
        int low = p >> 18;
        int r = atomicAdd(&lcur[low], 1);
        pool[lofs[low] + r] = p & 0x3FFFF;
    }
}

// ---------------- layer 0: gather rel_emb means + 32x32 matvecs -> h1 ----------------
// No LDS table (it killed occupancy); rel_emb (64KB) stays hot in L1/L2.
// Broadcast gather unrolled x4 for ILP.
__global__ __launch_bounds__(256) void k_layer0(const int* __restrict__ cnt, const int* __restrict__ offs,
                                                const int* __restrict__ pool, const float* __restrict__ rel_emb,
                                                const float* __restrict__ W_out, const float* __restrict__ b_out,
                                                const float* __restrict__ W_in, const float* __restrict__ b_in,
                                                const int* __restrict__ deg1o, float* __restrict__ h1) {
    __shared__ float S[4][64];
    int t = threadIdx.x;
    int nl = t >> 6;
    int lane = t & 63;
    int half = lane >> 5;   // 0 = out(src-agg), 1 = in(dst-agg)
    int k = lane & 31;
    int n = blockIdx.x * 4 + nl;        // grid exact: N1 % 4 == 0
    int ci = (half ? IC0D : IC0S) + n;
    int dg = cnt[ci];
    int off = offs[ci];
    float acc = 0.0f;
    for (int cb = 0; cb < dg; cb += 32) {
        int rem = dg - cb; if (rem > 32) rem = 32;
        int ty_all = (k < rem) ? pool[off + cb + k] : 0;
        int i2 = 0;
        for (; i2 + 4 <= rem; i2 += 4) {
            int t0 = __shfl(ty_all, i2,     32);
            int t1 = __shfl(ty_all, i2 + 1, 32);
            int t2 = __shfl(ty_all, i2 + 2, 32);
            int t3 = __shfl(ty_all, i2 + 3, 32);
            float a0 = rel_emb[t0 * 32 + k];
            float a1 = rel_emb[t1 * 32 + k];
            float a2 = rel_emb[t2 * 32 + k];
            float a3 = rel_emb[t3 * 32 + k];
            acc += a0; acc += a1; acc += a2; acc += a3;
        }
        for (; i2 < rem; i2++) {
            int ty = __shfl(ty_all, i2, 32);
            acc += rel_emb[ty * 32 + k];
        }
    }
    S[nl][lane] = (dg > 0) ? acc / (float)dg : 0.0f;
    __syncthreads();
    const float* W = half ? W_in : W_out;
    float b = half ? b_in[k] : b_out[k];
    float r = 0.0f;
    if (dg > 0) {
        float d = 0.0f;
#pragma unroll
        for (int kk = 0; kk < 32; kk++) d += S[nl][half * 32 + kk] * W[kk * 32 + k];
        r = d + b;
    }
    h1[(size_t)n * 64 + lane] = r * rsqrtf(fmaxf((float)deg1o[n], 1.0f));
}

// ---------------- conv1 with fused gather (unroll x4), writes h2 as bf16 ----------------
__global__ __launch_bounds__(256) void k_conv1g(const float* __restrict__ h1,
                                                const int* __restrict__ cnt, const int* __restrict__ offs,
                                                const int* __restrict__ pool, const int* __restrict__ deg2o,
                                                const float* __restrict__ W1, const float* __restrict__ b1,
                                                __bf16* __restrict__ h2b) {
    __shared__ float row[8][64];
    int base = blockIdx.x * 8;
    int t = threadIdx.x;
    int wave = t >> 6, lane = t & 63;
#pragma unroll
    for (int rr = 0; rr < 2; rr++) {
        int m = wave * 2 + rr;
        int rg = base + m;                       // grid exact: rg < N2
        int dg = cnt[IC1 + rg];
        int off = offs[IC1 + rg];
        float acc = 0.0f;
        for (int cb = 0; cb < dg; cb += 64) {
            int rem = dg - cb; if (rem > 64) rem = 64;
            int s_all = (lane < rem) ? pool[off + cb + lane] : 0;
            int i = 0;
            for (; i + 4 <= rem; i += 4) {
                int s0 = __shfl(s_all, i,     64);
                int s1 = __shfl(s_all, i + 1, 64);
                int s2 = __shfl(s_all, i + 2, 64);
                int s3 = __shfl(s_all, i + 3, 64);
                float a0 = h1[(size_t)s0 * 64 + lane];
                float a1 = h1[(size_t)s1 * 64 + lane];
                float a2 = h1[(size_t)s2 * 64 + lane];
                float a3 = h1[(size_t)s3 * 64 + lane];
                acc += a0; acc += a1; acc += a2; acc += a3;
            }
            for (; i < rem; i++) {
                int s = __shfl(s_all, i, 64);
                acc += h1[(size_t)s * 64 + lane];
            }
        }
        row[m][lane] = acc * rsqrtf(fmaxf((float)dg, 1.0f));
    }
    __syncthreads();
    float acc8[8] = {0, 0, 0, 0, 0, 0, 0, 0};
    for (int k = 0; k < 64; k++) {
        float w = W1[k * 256 + t];
#pragma unroll
        for (int m = 0; m < 8; m++) acc8[m] += row[m][k] * w;
    }
    float bb = b1[t];
#pragma unroll
    for (int m = 0; m < 8; m++) {
        float v = fmaxf(acc8[m] + bb, 0.0f) * rsqrtf(fmaxf((float)deg2o[base + m], 1.0f));
        h2b[(size_t)(base + m) * 256 + t] = (__bf16)v;
    }
}

// ---------------- pack W (K x 256 f32, row-major) into MFMA B-fragment order (bf16) ----------------
__global__ void k_pack(const float* __restrict__ W, __bf16* __restrict__ Wp, int ksteps) {
    int idx = blockIdx.x * 256 + threadIdx.x;
    int j = idx & 7;
    int lane = (idx >> 3) & 63;
    int rest = idx >> 9;
    int ks = rest % ksteps;
    int tn = rest / ksteps;
    int k = ks * 32 + ((lane >> 4) * 8) + j;
    int n = tn * 16 + (lane & 15);
    Wp[idx] = (__bf16)W[k * 256 + n];
}

// ---------------- conv2 MFMA with fused gather (bf16 h2, unroll x2) ----------------
__global__ __launch_bounds__(256) void k_conv2g(const __bf16* __restrict__ h2b,
                                                const int* __restrict__ cnt, const int* __restrict__ offs,
                                                const int* __restrict__ pool,
                                                const __bf16* __restrict__ W2p,
                                                const float* __restrict__ b2v,
                                                __bf16* __restrict__ x3b) {
    __shared__ __bf16 At[64][264];   // +8 pad -> 2-way LDS conflicts only
    int t = threadIdx.x;
    int base = blockIdx.x * 64;
    int wave = t >> 6, lane = t & 63;
#pragma unroll 1
    for (int rr = 0; rr < 16; rr++) {
        int row = wave * 16 + rr;
        int rg = base + row;
        float a0 = 0.f, a1 = 0.f, a2 = 0.f, a3 = 0.f;
        int dg = 0;
        if (rg < N3) {
            dg = cnt[IC2 + rg];
            int off = offs[IC2 + rg];
            for (int cb = 0; cb < dg; cb += 64) {
                int rem = dg - cb; if (rem > 64) rem = 64;
                int s_all = (lane < rem) ? pool[off + cb + lane] : 0;
                int i = 0;
                for (; i + 2 <= rem; i += 2) {
                    int s0 = __shfl(s_all, i,     64);
                    int s1 = __shfl(s_all, i + 1, 64);
                    union { ushort4 u; __bf16 b[4]; } v0, v1;
                    v0.u = *(const ushort4*)(h2b + (size_t)s0 * 256 + lane * 4);
                    v1.u = *(const ushort4*)(h2b + (size_t)s1 * 256 + lane * 4);
                    a0 += (float)v0.b[0] + (float)v1.b[0];
                    a1 += (float)v0.b[1] + (float)v1.b[1];
                    a2 += (float)v0.b[2] + (float)v1.b[2];
                    a3 += (float)v0.b[3] + (float)v1.b[3];
                }
                if (i < rem) {
                    int s0 = __shfl(s_all, i, 64);
                    union { ushort4 u; __bf16 b[4]; } v0;
                    v0.u = *(const ushort4*)(h2b + (size_t)s0 * 256 + lane * 4);
                    a0 += (float)v0.b[0]; a1 += (float)v0.b[1];
                    a2 += (float)v0.b[2]; a3 += (float)v0.b[3];
                }
            }
        }
        float sc = rsqrtf(fmaxf((float)dg, 1.0f));
        union { __bf16 b[4]; uint2 u; } cv;
        cv.b[0] = (__bf16)(a0 * sc); cv.b[1] = (__bf16)(a1 * sc);
        cv.b[2] = (__bf16)(a2 * sc); cv.b[3] = (__bf16)(a3 * sc);
        *(uint2*)&At[row][lane * 4] = cv.u;
    }
    __syncthreads();
    int q = lane >> 4, r16 = lane & 15;
    f32x4 acc[4][4] = {};
    for (int ks = 0; ks < 8; ks++) {
        bf16x8 a[4], b[4];
        int ko = ks * 32 + q * 8;
#pragma unroll
        for (int mt = 0; mt < 4; mt++)
            a[mt] = *(const bf16x8*)&At[mt * 16 + r16][ko];
#pragma unroll
        for (int i = 0; i < 4; i++) {
            int tn = wave * 4 + i;
            b[i] = *(const bf16x8*)&W2p[((size_t)(tn * 8 + ks) * 64 + lane) * 8];
        }
#pragma unroll
        for (int mt = 0; mt < 4; mt++)
#pragma unroll
            for (int i = 0; i < 4; i++)
                acc[mt][i] = __builtin_amdgcn_mfma_f32_16x16x32_bf16(a[mt], b[i], acc[mt][i], 0, 0, 0);
    }
#pragma unroll
    for (int mt = 0; mt < 4; mt++) {
#pragma unroll
        for (int i = 0; i < 4; i++) {
            int col = (wave * 4 + i) * 16 + r16;
            float bb = b2v[col];
#pragma unroll
            for (int rr = 0; rr < 4; rr++) {
                int row = base + mt * 16 + q * 4 + rr;
                if (row < N3)
                    x3b[(size_t)row * 256 + col] = (__bf16)fmaxf(acc[mt][i][rr] + bb, 0.0f);
            }
        }
    }
}

// ---------------- final via MFMA: out = [x3b[ss], x3b[sd]] @ Wfc + bfc ----------------
__global__ __launch_bounds__(256) void k_final_mfma(const int* __restrict__ ss, const int* __restrict__ sd,
                                                    const __bf16* __restrict__ x3b,
                                                    const __bf16* __restrict__ Wp,
                                                    const float* __restrict__ bfc,
                                                    float* __restrict__ out) {
    __shared__ __bf16 At[64][520];   // +8 pad -> 2-way LDS conflicts only
    __shared__ int eidx[128];
    int t = threadIdx.x;
    int base = blockIdx.x * 64;
    if (t < 64)       { int e = base + t;      eidx[t] = ss[e < ESUB ? e : ESUB - 1]; }
    else if (t < 128) { int e = base + t - 64; eidx[t] = sd[e < ESUB ? e : ESUB - 1]; }
    __syncthreads();
#pragma unroll
    for (int it = 0; it < 16; it++) {
        int c = it * 256 + t;       // 0..4095
        int row = c >> 6;           // 0..63
        int cpos = c & 63;          // 16B chunk within 512-elem row
        int half = cpos >> 5;
        int off8 = (cpos & 31) * 8;
        int node = eidx[half * 64 + row];
        uint4 v = *(const uint4*)(x3b + (size_t)node * 256 + off8);
        *(uint4*)&At[row][half * 256 + off8] = v;
    }
    __syncthreads();
    int wave = t >> 6, lane = t & 63;
    int q = lane >> 4, r16 = lane & 15;
    f32x4 acc[4][4] = {};
    for (int ks = 0; ks < 16; ks++) {
        bf16x8 a[4], b[4];
        int ko = ks * 32 + q * 8;
#pragma unroll
        for (int mt = 0; mt < 4; mt++)
            a[mt] = *(const bf16x8*)&At[mt * 16 + r16][ko];
#pragma unroll
        for (int i = 0; i < 4; i++) {
            int tn = wave * 4 + i;
            b[i] = *(const bf16x8*)&Wp[((size_t)(tn * 16 + ks) * 64 + lane) * 8];
        }
#pragma unroll
        for (int mt = 0; mt < 4; mt++)
#pragma unroll
            for (int i = 0; i < 4; i++)
                acc[mt][i] = __builtin_amdgcn_mfma_f32_16x16x32_bf16(a[mt], b[i], acc[mt][i], 0, 0, 0);
    }
#pragma unroll
    for (int mt = 0; mt < 4; mt++) {
#pragma unroll
        for (int i = 0; i < 4; i++) {
            int col = (wave * 4 + i) * 16 + r16;
            float bb = bfc[col];
#pragma unroll
            for (int rr = 0; rr < 4; rr++) {
                int row = base + mt * 16 + q * 4 + rr;
                if (row < ESUB)
                    out[(size_t)row * 256 + col] = acc[mt][i][rr] + bb;
            }
        }
    }
}

extern "C" void kernel_launch(void* const* d_in, const int* in_sizes, int n_in,
                              void* d_out, int out_size, void* d_ws, size_t ws_size,
                              hipStream_t stream) {
    const int* e0_type = (const int*)d_in[0];
    const int* e0_src  = (const int*)d_in[1];
    const int* e0_dst  = (const int*)d_in[2];
    const int* e1_src  = (const int*)d_in[3];
    const int* e1_dst  = (const int*)d_in[4];
    const int* e2_src  = (const int*)d_in[5];
    const int* e2_dst  = (const int*)d_in[6];
    const int* sub_src = (const int*)d_in[7];
    const int* sub_dst = (const int*)d_in[8];
    const float* rel_emb = (const float*)d_in[9];
    const float* W_out   = (const float*)d_in[10];
    const float* b_out   = (const float*)d_in[11];
    const float* W_in    = (const float*)d_in[12];
    const float* b_in    = (const float*)d_in[13];
    const float* W1      = (const float*)d_in[14];
    const float* b1      = (const float*)d_in[15];
    const float* W2      = (const float*)d_in[16];
    const float* b2v     = (const float*)d_in[17];
    const float* Wfc     = (const float*)d_in[18];
    const float* bfc     = (const float*)d_in[19];
    float* out = (float*)d_out;

    // ---- workspace layout (4-byte units) ----
    // [cnt | ccur | deg1o | deg2o | offs(+1) | bsum | bscan | pool | cpool | h1 | h2 | Wfcp | W2p]
    int* cnt   = (int*)d_ws;
    int* ccur  = cnt + LTOT;             // 1024 coarse-bucket cursors
    int* deg1o = ccur + CCTOT;           // e1_src out-degree over N1
    int* deg2o = deg1o + N1;             // e2_src out-degree over N2
    int* offs  = deg2o + N2;             // LTOT+1 (last = grand total)
    int* bsum  = offs + LTOT + 1;
    int* bscan = bsum + 512;
    int* pool  = bscan + 512;            // POOLCAP slots; g2 = pool[0..E2)
    int* cpool = pool + POOLCAP;         // coarse (pass-A) pool, same capacity
    float* h1  = (float*)(cpool + POOLCAP);          // N1*64 f32
    float* h2f = h1 + (size_t)N1 * 64;               // region sized N2*256 f32
    __bf16* h2b = (__bf16*)h2f;                      // h2 stored as bf16 inside it
    __bf16* Wfcp = (__bf16*)(h2f + (size_t)N2 * 256); // 512*256 bf16
    __bf16* W2p  = Wfcp + 131072;                    // 256*256 bf16
    // x3b aliases pool-after-g2 + cpool + head of h1 (all dead by conv2g)
    __bf16* x3b  = (__bf16*)(pool + E2);

    const int BT = 256;

    // zero cnt + ccur + deg1o + deg2o (contiguous, ~3.2 MB)
    hipMemsetAsync(d_ws, 0, (size_t)(LTOT + CCTOT + N1 + N2) * sizeof(int), stream);

    // pack weights (independent of zeroed region)
    k_pack<<<512, BT, 0, stream>>>(Wfc, Wfcp, 16);
    k_pack<<<256, BT, 0, stream>>>(W2, W2p, 8);

    // count
    k_cnt0<<<(E0 + BT - 1) / BT, BT, 0, stream>>>(e0_src, e0_dst, cnt);
    k_cnt2<<<(E1 + BT - 1) / BT, BT, 0, stream>>>(e1_src, e1_dst, E1, deg1o, cnt, IC1);
    k_cnt2<<<(E2 + BT - 1) / BT, BT, 0, stream>>>(e2_src, e2_dst, E2, deg2o, cnt, IC2);

    // exclusive scan of cnt -> offs (+ grand total at offs[LTOT])
    k_scan1<<<NBLK, BT, 0, stream>>>(cnt, offs, bsum);
    k_scan2<<<1, BT, 0, stream>>>(bsum, bscan);
    k_scan3<<<(LTOT + BT - 1) / BT, BT, 0, stream>>>(offs, bscan, bsum);

    // pass A: dense coarse binning
    int nbA0 = (E0 + BINCHUNK - 1) / BINCHUNK;
    int nbA1 = (E1 + BINCHUNK - 1) / BINCHUNK;
    int nbA2 = (E2 + BINCHUNK - 1) / BINCHUNK;
    k_binA<<<nbA2, BT, 0, stream>>>(e2_dst, e2_src, E2, offs, IC2, ccur, CC2, cpool);
    k_binA0<<<nbA0, BT, 0, stream>>>(e0_type, e0_src, e0_dst, offs, ccur, cpool);
    k_binA<<<nbA1, BT, 0, stream>>>(e1_dst, e1_src, E1, offs, IC1, ccur, CC1, cpool);

    // pass B: L2-local scatter into exact CSR slots
    k_binB<<<NC2, BT, 0, stream>>>(offs, IC2,  N3, cpool, pool);
    k_binB<<<NC0, BT, 0, stream>>>(offs, IC0S, N1, cpool, pool);
    k_binB<<<NC0, BT, 0, stream>>>(offs, IC0D, N1, cpool, pool);
    k_binB<<<NC1, BT, 0, stream>>>(offs, IC1,  N2, cpool, pool);

    // layer 0: gather + combine -> h1
    k_layer0<<<N1 / 4, BT, 0, stream>>>(cnt, offs, pool, rel_emb, W_out, b_out, W_in, b_in, deg1o, h1);

    // conv1 (fused gather) -> h2 (bf16)
    k_conv1g<<<N2 / 8, BT, 0, stream>>>(h1, cnt, offs, pool, deg2o, W1, b1, h2b);

    // conv2 (fused gather, MFMA) -> x3b
    k_conv2g<<<(N3 + 63) / 64, BT, 0, stream>>>(h2b, cnt, offs, pool, W2p, b2v, x3b);

    // final edge MLP (MFMA)
    k_final_mfma<<<(ESUB + 63) / 64, BT, 0, stream>>>(sub_src, sub_dst, x3b, Wfcp, bfc, out);
}